// Round 6
// baseline (3219.365 us; speedup 1.0000x reference)
//
#include <hip/hip_runtime.h>

typedef unsigned short u16;
typedef __attribute__((ext_vector_type(8))) short frag8;
typedef __attribute__((ext_vector_type(4))) float f32x4;
typedef __attribute__((ext_vector_type(8))) unsigned short u16x8;

#define LDST 40   // LDS row stride (elements); 32+8 pad to spread b128 reads over banks

__device__ __forceinline__ float b2f(u16 u) {
  union { unsigned int i; float f; } v; v.i = ((unsigned int)u) << 16; return v.f;
}
__device__ __forceinline__ u16 f2b(float f) {
  union { float f; unsigned int i; } v; v.f = f;
  unsigned int x = v.i;
  x += 0x7fffu + ((x >> 16) & 1u);
  return (u16)(x >> 16);
}

// ---------------------------------------------------------------------------
// Prep kernels — f32 inputs; everything GEMM-facing becomes bf16 once here.
// ---------------------------------------------------------------------------
__global__ void cvt3(const float* __restrict__ s0, const float* __restrict__ s1,
                     const float* __restrict__ s2, u16* __restrict__ d0,
                     u16* __restrict__ d1, u16* __restrict__ d2) {
  int i = blockIdx.x * 256 + threadIdx.x;   // 3 * 3145728
  int which = i / 3145728;
  int j = i - which * 3145728;
  const float* s = (which == 0) ? s0 : (which == 1 ? s1 : s2);
  u16* d = (which == 0) ? d0 : (which == 1 ? d1 : d2);
  d[j] = f2b(s[j]);
}

__global__ void cvt2(const float* __restrict__ s0, const float* __restrict__ s1,
                     u16* __restrict__ d0, u16* __restrict__ d1) {
  int i = blockIdx.x * 256 + threadIdx.x;   // 2 * 1048576
  if (i < 1048576) d0[i] = f2b(s0[i]);
  else             d1[i - 1048576] = f2b(s1[i - 1048576]);
}

// Split g1_wih [3072, 642] (f32) into bf16 Wc [3072,512] and Wd [3072,160]
// (zero-padded cols 130..159).
__global__ void prep_w1(const float* __restrict__ wih, u16* __restrict__ Wc, u16* __restrict__ Wd) {
  int i = blockIdx.x * 256 + threadIdx.x;
  const int NC = 3072 * 512;
  if (i < NC) {
    int n = i >> 9, k = i & 511;
    Wc[i] = f2b(wih[n * 642 + k]);
  } else {
    int j = i - NC;                 // 0 .. 3072*160-1
    int n = j / 160, k = j - n * 160;
    Wd[j] = (k < 130) ? f2b(wih[n * 642 + 512 + k]) : (u16)0;
  }
}

// fco_w [130,1024] f32 -> bf16 WBy [256,1024], zero rows 130..255
__global__ void prep_wby(const float* __restrict__ fcow, u16* __restrict__ wby) {
  int i = blockIdx.x * 256 + threadIdx.x;   // 256*1024
  int n = i >> 10;
  wby[i] = (n < 130) ? f2b(fcow[i]) : (u16)0;
}

// ---------------------------------------------------------------------------
// bt-GEMM: C[m][n] = sum_k A[m][k]*Bsel[n'][k].  A,B bf16.
//   Bsel/n' per 128-tile: n0<n_split -> B0,n'=n else B1,n'=n-n_split
// 128x128 tile, BK=32, 256 thr = 4 waves (2x2 of 64x64), mfma 16x16x32 bf16.
// Double-buffered LDS (one barrier per K-step); VGPR-mediated staging so
// global loads for tile k+32 issue before computing tile k.
// If dA != nullptr: A is read directly from target[B=128,T=256,D=130] f32 with
// the prev-shift (row m=e*128+b -> target[b, e*16+tstep-1, k], zero-padded)
// — used by the mode-2 gi1 GEMM only (K=160).
// K % 32 == 0, K >= 64 not required (loop handles K=160 etc.).
// Epilogue modes:
//  0: out0(bf16)[m*N+n] = acc + bias0[n]
//  1: t=tanh(acc+bias0[n]); n<1024 -> h1 else h2; write f32 (fout*) AND bf16 (out*)
//  2: out0(bf16)[m*N+n] = acc + b2f(addmat[m*N+n])                    [N=3072]
//  3: n<3072 -> out0+bias0 (gi2) ; else out1+bias1 (gh1)              [N=6144]
//  4: n<3072 -> out0+bias0 (gh2) ; 3072<=n<3202 -> y(f32) scatter     [N=3328]
// ---------------------------------------------------------------------------
__global__ __launch_bounds__(256) void gemm_bt(
    const u16* __restrict__ A, int lda, const float* __restrict__ dA,
    const u16* __restrict__ B0, const u16* __restrict__ B1, int ldb, int n_split,
    int N, int K, int mode, int tstep,
    const float* __restrict__ bias0, const float* __restrict__ bias1,
    u16* __restrict__ out0, u16* __restrict__ out1,
    const u16* __restrict__ addmat,
    float* __restrict__ fout0, float* __restrict__ fout1)
{
  __shared__ u16 As0[128 * LDST], As1[128 * LDST];
  __shared__ u16 Bs0[128 * LDST], Bs1[128 * LDST];

  const int tid = threadIdx.x;
  const int wave = tid >> 6;
  const int lane = tid & 63;
  const int m0 = blockIdx.y * 128;
  const int n0 = blockIdx.x * 128;
  const int wm = (wave >> 1) * 64;
  const int wn = (wave & 1) * 64;
  const int lr = lane & 15;
  const int lq = lane >> 4;

  const u16* Bsel;
  int nb0;
  if (n0 < n_split) { Bsel = B0; nb0 = n0; }
  else              { Bsel = B1; nb0 = n0 - n_split; }

  f32x4 acc[4][4] = {};

  // staging: thread tid covers rows {srow, 64+srow}, 16B chunk (tid&3)*8
  const int srow = tid >> 2;
  const int skc  = (tid & 3) * 8;

  auto ldA = [&](int k0, int rowoff) -> u16x8 {
    if (dA == nullptr) {
      return *(const u16x8*)&A[(size_t)(m0 + rowoff + srow) * lda + k0 + skc];
    }
    int mrow = m0 + rowoff + srow;
    int e = mrow >> 7, b = mrow & 127;
    int tt = e * 16 + tstep;
    const float* trow = dA + (size_t)(b * 256 + tt - 1) * 130;
    u16x8 r;
#pragma unroll
    for (int j = 0; j < 8; ++j) {
      int k = k0 + skc + j;
      float v = (tt > 0 && k < 130) ? trow[k] : 0.f;
      r[j] = f2b(v);
    }
    return r;
  };
  auto ldB = [&](int k0, int rowoff) -> u16x8 {
    return *(const u16x8*)&Bsel[(size_t)(nb0 + rowoff + srow) * ldb + k0 + skc];
  };

#define STORE_TILE(AsX, BsX)                               \
  do {                                                     \
    *(u16x8*)&AsX[srow * LDST + skc] = ra0;                \
    *(u16x8*)&AsX[(64 + srow) * LDST + skc] = ra1;         \
    *(u16x8*)&BsX[srow * LDST + skc] = rb0;                \
    *(u16x8*)&BsX[(64 + srow) * LDST + skc] = rb1;         \
  } while (0)

#define LOAD_TILE(kk)                                      \
  do {                                                     \
    ra0 = ldA(kk, 0); ra1 = ldA(kk, 64);                   \
    rb0 = ldB(kk, 0); rb1 = ldB(kk, 64);                   \
  } while (0)

#define COMPUTE(AsX, BsX)                                                       \
  do {                                                                          \
    frag8 af[4], bfv[4];                                                        \
    _Pragma("unroll")                                                           \
    for (int i = 0; i < 4; ++i)                                                 \
      af[i] = *(const frag8*)&AsX[(wm + i * 16 + lr) * LDST + lq * 8];          \
    _Pragma("unroll")                                                           \
    for (int j = 0; j < 4; ++j)                                                 \
      bfv[j] = *(const frag8*)&BsX[(wn + j * 16 + lr) * LDST + lq * 8];         \
    _Pragma("unroll")                                                           \
    for (int i = 0; i < 4; ++i)                                                 \
      _Pragma("unroll")                                                         \
      for (int j = 0; j < 4; ++j)                                               \
        acc[i][j] = __builtin_amdgcn_mfma_f32_16x16x32_bf16(af[i], bfv[j],      \
                                                            acc[i][j], 0, 0, 0);\
  } while (0)

  u16x8 ra0, ra1, rb0, rb1;
  LOAD_TILE(0);
  STORE_TILE(As0, Bs0);

  for (int k0 = 0; k0 < K; k0 += 64) {
    __syncthreads();                       // buf0 (tile k0) visible; buf1 free
    bool m1 = (k0 + 32 < K);
    bool m2 = (k0 + 64 < K);
    if (m1) LOAD_TILE(k0 + 32);
    COMPUTE(As0, Bs0);                     // tile k0
    if (m1) STORE_TILE(As1, Bs1);
    __syncthreads();                       // buf1 (tile k0+32) visible; buf0 free
    if (m2) LOAD_TILE(k0 + 64);
    if (m1) COMPUTE(As1, Bs1);             // tile k0+32
    if (m2) STORE_TILE(As0, Bs0);
  }

  // C/D layout: col = lane&15 (n), row = (lane>>4)*4 + reg (m).
#pragma unroll
  for (int i = 0; i < 4; ++i) {
#pragma unroll
    for (int r = 0; r < 4; ++r) {
      int m = m0 + wm + i * 16 + lq * 4 + r;
#pragma unroll
      for (int j = 0; j < 4; ++j) {
        int n = n0 + wn + j * 16 + lr;
        float v = acc[i][j][r];
        if (mode == 0) {
          out0[(size_t)m * N + n] = f2b(v + bias0[n]);
        } else if (mode == 1) {
          float t = tanhf(v + bias0[n]);
          if (n < 1024) { fout0[(size_t)m * 1024 + n] = t;          out0[(size_t)m * 1024 + n] = f2b(t); }
          else          { fout1[(size_t)m * 1024 + (n - 1024)] = t; out1[(size_t)m * 1024 + (n - 1024)] = f2b(t); }
        } else if (mode == 2) {
          out0[(size_t)m * N + n] = f2b(v + b2f(addmat[(size_t)m * N + n]));
        } else if (mode == 3) {
          if (n < 3072) out0[(size_t)m * 3072 + n] = f2b(v + bias0[n]);
          else          out1[(size_t)m * 3072 + (n - 3072)] = f2b(v + bias1[n - 3072]);
        } else { // mode 4
          if (n < 3072) {
            out0[(size_t)m * 3072 + n] = f2b(v + bias0[n]);
          } else if (n < 3202) {
            int d = n - 3072;
            int b = m & 127, e = m >> 7;
            fout0[(size_t)((b << 8) + (e << 4) + tstep) * 130 + d] = v + bias1[d];
          }
        }
      }
    }
  }
#undef STORE_TILE
#undef LOAD_TILE
#undef COMPUTE
}

// ---------------------------------------------------------------------------
// GRU combine: h = (1-z)*n + z*h. gi/gh bf16 [2048,3072] (biases folded),
// h32 f32 [2048,1024] master state (in place), hb16 bf16 shadow for GEMM A.
// ---------------------------------------------------------------------------
__global__ __launch_bounds__(256) void gru_combine(
    const u16* __restrict__ gi, const u16* __restrict__ gh,
    float* __restrict__ h32, u16* __restrict__ hb16)
{
  int idx = blockIdx.x * 256 + threadIdx.x;   // 0 .. 2048*128-1
  int m = idx >> 7;
  int j0 = (idx & 127) << 3;
  const size_t gb = (size_t)m * 3072 + j0;
  const size_t hb = (size_t)m * 1024 + j0;
  u16x8 ir = *(const u16x8*)&gi[gb];
  u16x8 iz = *(const u16x8*)&gi[gb + 1024];
  u16x8 in_ = *(const u16x8*)&gi[gb + 2048];
  u16x8 hr = *(const u16x8*)&gh[gb];
  u16x8 hz = *(const u16x8*)&gh[gb + 1024];
  u16x8 hn = *(const u16x8*)&gh[gb + 2048];
  f32x4 h0 = *(const f32x4*)&h32[hb];
  f32x4 h1v = *(const f32x4*)&h32[hb + 4];
  f32x4 o0, o1;
  u16x8 ob;
#pragma unroll
  for (int q = 0; q < 8; ++q) {
    float r = 1.f / (1.f + __expf(-(b2f(ir[q]) + b2f(hr[q]))));
    float z = 1.f / (1.f + __expf(-(b2f(iz[q]) + b2f(hz[q]))));
    float nn = tanhf(b2f(in_[q]) + r * b2f(hn[q]));
    float hh = (q < 4) ? h0[q & 3] : h1v[q & 3];
    float res = (1.f - z) * nn + z * hh;
    if (q < 4) o0[q & 3] = res; else o1[q & 3] = res;
    ob[q] = f2b(res);
  }
  *(f32x4*)&h32[hb] = o0;
  *(f32x4*)&h32[hb + 4] = o1;
  *(u16x8*)&hb16[hb] = ob;
}

// ---------------------------------------------------------------------------
extern "C" void kernel_launch(void* const* d_in, const int* in_sizes, int n_in,
                              void* d_out, int out_size, void* d_ws, size_t ws_size,
                              hipStream_t stream)
{
  const float* c      = (const float*)d_in[0];
  const float* target = (const float*)d_in[1];
  const float* fiw    = (const float*)d_in[4];
  const float* fib    = (const float*)d_in[5];
  const float* g1wih  = (const float*)d_in[6];
  const float* g1whh  = (const float*)d_in[7];
  const float* g1bih  = (const float*)d_in[8];
  const float* g1bhh  = (const float*)d_in[9];
  const float* g2wih  = (const float*)d_in[10];
  const float* g2whh  = (const float*)d_in[11];
  const float* g2bih  = (const float*)d_in[12];
  const float* g2bhh  = (const float*)d_in[13];
  const float* fcow   = (const float*)d_in[14];
  const float* fcob   = (const float*)d_in[15];
  float* out = (float*)d_out;

  char* wsp = (char*)d_ws;
  size_t off = 0;
  auto takeb = [&](size_t bytes) {
    void* p = (void*)(wsp + off);
    off += bytes;
    off = (off + 255) & ~(size_t)255;
    return p;
  };
  float* h1f = (float*)takeb((size_t)2048 * 1024 * 4);
  float* h2f = (float*)takeb((size_t)2048 * 1024 * 4);
  u16* h1b   = (u16*)takeb((size_t)2048 * 1024 * 2);
  u16* h2b   = (u16*)takeb((size_t)2048 * 1024 * 2);
  u16* gic   = (u16*)takeb((size_t)2048 * 3072 * 2);
  u16* gib   = (u16*)takeb((size_t)2048 * 3072 * 2);
  u16* gh1   = (u16*)takeb((size_t)2048 * 3072 * 2);
  u16* gh2   = (u16*)takeb((size_t)2048 * 3072 * 2);
  u16* cbf   = (u16*)takeb((size_t)2048 * 512 * 2);
  u16* Wfi   = (u16*)takeb((size_t)2048 * 512 * 2);
  u16* Wc    = (u16*)takeb((size_t)3072 * 512 * 2);
  u16* Wd    = (u16*)takeb((size_t)3072 * 160 * 2);
  u16* W1h   = (u16*)takeb((size_t)3072 * 1024 * 2);
  u16* W2i   = (u16*)takeb((size_t)3072 * 1024 * 2);
  u16* W2h   = (u16*)takeb((size_t)3072 * 1024 * 2);
  u16* WBy   = (u16*)takeb((size_t)256 * 1024 * 2);
  // total ~94 MiB
  (void)ws_size; (void)in_sizes; (void)n_in; (void)out_size;

  const int BIG = 1 << 30;   // n_split sentinel: always B0

  // --- one-time prep: conversions to bf16 (2+2 kernels) ---
  cvt2<<<8192, 256, 0, stream>>>(c, fiw, cbf, Wfi);
  cvt3<<<36864, 256, 0, stream>>>(g1whh, g2wih, g2whh, W1h, W2i, W2h);
  prep_w1 <<<8064, 256, 0, stream>>>(g1wih, Wc, Wd);
  prep_wby<<<1024, 256, 0, stream>>>(fcow, WBy);

  // --- init ---
  // h1,h2 = tanh(c @ fiw.T + fib)  (f32 + bf16 shadow)
  gemm_bt<<<dim3(16, 16), 256, 0, stream>>>(cbf, 512, nullptr, Wfi, nullptr, 512, BIG,
                                            2048, 512, 1, 0, fib, nullptr,
                                            h1b, h2b, nullptr, h1f, h2f);
  // gi_c = c @ Wc.T + g1bih
  gemm_bt<<<dim3(24, 16), 256, 0, stream>>>(cbf, 512, nullptr, Wc, nullptr, 512, BIG,
                                            3072, 512, 0, 0, g1bih, nullptr,
                                            gic, nullptr, nullptr, nullptr, nullptr);
  // gh1 = h1 @ g1whh.T + g1bhh
  gemm_bt<<<dim3(24, 16), 256, 0, stream>>>(h1b, 1024, nullptr, W1h, nullptr, 1024, BIG,
                                            3072, 1024, 0, 0, g1bhh, nullptr,
                                            gh1, nullptr, nullptr, nullptr, nullptr);
  // gh2 = h2 @ g2whh.T + g2bhh
  gemm_bt<<<dim3(24, 16), 256, 0, stream>>>(h2b, 1024, nullptr, W2h, nullptr, 1024, BIG,
                                            3072, 1024, 0, 0, g2bhh, nullptr,
                                            gh2, nullptr, nullptr, nullptr, nullptr);

  // --- recurrence ---
  for (int t = 0; t < 16; ++t) {
    // gi1 = prev_t @ Wd.T + gi_c   (A read directly from target, shifted)
    gemm_bt<<<dim3(24, 16), 256, 0, stream>>>(nullptr, 160, target, Wd, nullptr, 160, BIG,
                                              3072, 160, 2, t, nullptr, nullptr,
                                              gib, nullptr, gic, nullptr, nullptr);
    gru_combine<<<1024, 256, 0, stream>>>(gib, gh1, h1f, h1b);   // h1 <- GRU1
    // gi2 = h1 @ g2wih.T + g2bih ; gh1_next = h1 @ g1whh.T + g1bhh
    gemm_bt<<<dim3(48, 16), 256, 0, stream>>>(h1b, 1024, nullptr, W2i, W1h, 1024, 3072,
                                              6144, 1024, 3, 0, g2bih, g1bhh,
                                              gib, gh1, nullptr, nullptr, nullptr);
    gru_combine<<<1024, 256, 0, stream>>>(gib, gh2, h2f, h2b);   // h2 <- GRU2
    // gh2_next = h2 @ g2whh.T + g2bhh ; y = h2 @ fco_w.T + fco_b -> out (f32)
    gemm_bt<<<dim3(26, 16), 256, 0, stream>>>(h2b, 1024, nullptr, W2h, WBy, 1024, 3072,
                                              3328, 1024, 4, t, g2bhh, fcob,
                                              gh2, nullptr, nullptr, out, nullptr);
  }
}

// Round 7
// 2501.530 us; speedup vs baseline: 1.2870x; 1.2870x over previous
//
#include <hip/hip_runtime.h>

typedef unsigned short u16;
typedef __attribute__((ext_vector_type(8))) short frag8;
typedef __attribute__((ext_vector_type(4))) float f32x4;
typedef __attribute__((ext_vector_type(8))) unsigned short u16x8;

#define LDST 36   // LDS row stride (elems) = 18 dwords: b128 ops spread ~2-way over banks

__device__ __forceinline__ float b2f(u16 u) {
  union { unsigned int i; float f; } v; v.i = ((unsigned int)u) << 16; return v.f;
}
__device__ __forceinline__ u16 f2b(float f) {
  union { float f; unsigned int i; } v; v.f = f;
  unsigned int x = v.i;
  x += 0x7fffu + ((x >> 16) & 1u);
  return (u16)(x >> 16);
}

// ---------------------------------------------------------------------------
// Prep kernels — f32 inputs; everything GEMM-facing becomes bf16 once here.
// ---------------------------------------------------------------------------
__global__ void cvt3(const float* __restrict__ s0, const float* __restrict__ s1,
                     const float* __restrict__ s2, u16* __restrict__ d0,
                     u16* __restrict__ d1, u16* __restrict__ d2) {
  int i = blockIdx.x * 256 + threadIdx.x;   // 3 * 3145728
  int which = i / 3145728;
  int j = i - which * 3145728;
  const float* s = (which == 0) ? s0 : (which == 1 ? s1 : s2);
  u16* d = (which == 0) ? d0 : (which == 1 ? d1 : d2);
  d[j] = f2b(s[j]);
}

__global__ void cvt2(const float* __restrict__ s0, const float* __restrict__ s1,
                     u16* __restrict__ d0, u16* __restrict__ d1) {
  int i = blockIdx.x * 256 + threadIdx.x;   // 2 * 1048576
  if (i < 1048576) d0[i] = f2b(s0[i]);
  else             d1[i - 1048576] = f2b(s1[i - 1048576]);
}

// Split g1_wih [3072, 642] (f32) into bf16 Wc [3072,512] and Wd [3072,160]
// (zero-padded cols 130..159).
__global__ void prep_w1(const float* __restrict__ wih, u16* __restrict__ Wc, u16* __restrict__ Wd) {
  int i = blockIdx.x * 256 + threadIdx.x;
  const int NC = 3072 * 512;
  if (i < NC) {
    int n = i >> 9, k = i & 511;
    Wc[i] = f2b(wih[n * 642 + k]);
  } else {
    int j = i - NC;                 // 0 .. 3072*160-1
    int n = j / 160, k = j - n * 160;
    Wd[j] = (k < 130) ? f2b(wih[n * 642 + 512 + k]) : (u16)0;
  }
}

// fco_w [130,1024] f32 -> bf16 WBy [256,1024], zero rows 130..255
__global__ void prep_wby(const float* __restrict__ fcow, u16* __restrict__ wby) {
  int i = blockIdx.x * 256 + threadIdx.x;   // 256*1024
  int n = i >> 10;
  wby[i] = (n < 130) ? f2b(fcow[i]) : (u16)0;
}

// ---------------------------------------------------------------------------
// bt-GEMM: C[m][n] = sum_k A[m][k]*Bsel[n'][k].  A,B bf16.
//   Bsel/n' per 128-tile: n0<n_split -> B0,n'=n else B1,n'=n-n_split
// 128x128 tile, BK=32, **512 threads = 8 waves** (4x2 of 32m x 64n, acc 2x4):
// same grid, 2x waves/CU (24 at 3 blocks/CU) to cover the per-K-step latency
// chain — the grid (768 blocks max) caps blocks/CU at 3, so TLP must come
// from more waves per block. Single-buffer LDS (explicit dbuf measured 1.5x
// WORSE in r6: LDS+VGPR killed occupancy; compiler already hoists next-step
// global loads across the barrier). mfma 16x16x32 bf16, fp32 accum.
// If dA != nullptr: A read directly from target[B=128,T=256,D=130] f32 with
// the prev-shift (row m=e*128+b -> target[b, e*16+tstep-1, k], zero-padded).
// Epilogue modes:
//  0: out0(bf16)[m*N+n] = acc + bias0[n]
//  1: t=tanh(acc+bias0[n]); n<1024 -> h1 else h2; write f32 (fout*) AND bf16 (out*)
//  2: out0(bf16)[m*N+n] = acc + b2f(addmat[m*N+n])                    [N=3072]
//  3: n<3072 -> out0+bias0 (gi2) ; else out1+bias1 (gh1)              [N=6144]
//  4: n<3072 -> out0+bias0 (gh2) ; 3072<=n<3202 -> y(f32) scatter     [N=3328]
// ---------------------------------------------------------------------------
__global__ __launch_bounds__(512, 6) void gemm_bt(
    const u16* __restrict__ A, int lda, const float* __restrict__ dA,
    const u16* __restrict__ B0, const u16* __restrict__ B1, int ldb, int n_split,
    int N, int K, int mode, int tstep,
    const float* __restrict__ bias0, const float* __restrict__ bias1,
    u16* __restrict__ out0, u16* __restrict__ out1,
    const u16* __restrict__ addmat,
    float* __restrict__ fout0, float* __restrict__ fout1)
{
  __shared__ u16 As[128 * LDST];
  __shared__ u16 Bs[128 * LDST];

  const int tid = threadIdx.x;
  const int wave = tid >> 6;
  const int lane = tid & 63;
  const int m0 = blockIdx.y * 128;
  const int n0 = blockIdx.x * 128;
  const int wm = (wave & 3) * 32;    // wave m-offset (4 waves down)
  const int wn = (wave >> 2) * 64;   // wave n-offset (2 waves across)
  const int lr = lane & 15;
  const int lq = lane >> 4;

  const u16* Bsel;
  int nb0;
  if (n0 < n_split) { Bsel = B0; nb0 = n0; }
  else              { Bsel = B1; nb0 = n0 - n_split; }

  f32x4 acc[2][4] = {};

  // staging: thread tid covers row srow (0..127), 16B chunk (tid&3)*8
  const int srow = tid >> 2;
  const int skc  = (tid & 3) * 8;

  auto ldA = [&](int k0) -> u16x8 {
    if (dA == nullptr) {
      return *(const u16x8*)&A[(size_t)(m0 + srow) * lda + k0 + skc];
    }
    int mrow = m0 + srow;
    int e = mrow >> 7, b = mrow & 127;
    int tt = e * 16 + tstep;
    const float* trow = dA + (size_t)(b * 256 + tt - 1) * 130;
    u16x8 r;
#pragma unroll
    for (int j = 0; j < 8; ++j) {
      int k = k0 + skc + j;
      float v = (tt > 0 && k < 130) ? trow[k] : 0.f;
      r[j] = f2b(v);
    }
    return r;
  };

  for (int k0 = 0; k0 < K; k0 += 32) {
    u16x8 ra = ldA(k0);
    u16x8 rb = *(const u16x8*)&Bsel[(size_t)(nb0 + srow) * ldb + k0 + skc];
    *(u16x8*)&As[srow * LDST + skc] = ra;
    *(u16x8*)&Bs[srow * LDST + skc] = rb;
    __syncthreads();

    frag8 af[2], bfr[4];
#pragma unroll
    for (int i = 0; i < 2; ++i)
      af[i] = *(const frag8*)&As[(wm + i * 16 + lr) * LDST + lq * 8];
#pragma unroll
    for (int j = 0; j < 4; ++j)
      bfr[j] = *(const frag8*)&Bs[(wn + j * 16 + lr) * LDST + lq * 8];
#pragma unroll
    for (int i = 0; i < 2; ++i)
#pragma unroll
      for (int j = 0; j < 4; ++j)
        acc[i][j] = __builtin_amdgcn_mfma_f32_16x16x32_bf16(af[i], bfr[j], acc[i][j], 0, 0, 0);
    __syncthreads();
  }

  // C/D layout: col = lane&15 (n), row = (lane>>4)*4 + reg (m).
#pragma unroll
  for (int i = 0; i < 2; ++i) {
#pragma unroll
    for (int r = 0; r < 4; ++r) {
      int m = m0 + wm + i * 16 + lq * 4 + r;
#pragma unroll
      for (int j = 0; j < 4; ++j) {
        int n = n0 + wn + j * 16 + lr;
        float v = acc[i][j][r];
        if (mode == 0) {
          out0[(size_t)m * N + n] = f2b(v + bias0[n]);
        } else if (mode == 1) {
          float t = tanhf(v + bias0[n]);
          if (n < 1024) { fout0[(size_t)m * 1024 + n] = t;          out0[(size_t)m * 1024 + n] = f2b(t); }
          else          { fout1[(size_t)m * 1024 + (n - 1024)] = t; out1[(size_t)m * 1024 + (n - 1024)] = f2b(t); }
        } else if (mode == 2) {
          out0[(size_t)m * N + n] = f2b(v + b2f(addmat[(size_t)m * N + n]));
        } else if (mode == 3) {
          if (n < 3072) out0[(size_t)m * 3072 + n] = f2b(v + bias0[n]);
          else          out1[(size_t)m * 3072 + (n - 3072)] = f2b(v + bias1[n - 3072]);
        } else { // mode 4
          if (n < 3072) {
            out0[(size_t)m * 3072 + n] = f2b(v + bias0[n]);
          } else if (n < 3202) {
            int d = n - 3072;
            int b = m & 127, e = m >> 7;
            fout0[(size_t)((b << 8) + (e << 4) + tstep) * 130 + d] = v + bias1[d];
          }
        }
      }
    }
  }
}

// ---------------------------------------------------------------------------
// GRU combine: h = (1-z)*n + z*h. gi/gh bf16 [2048,3072] (biases folded),
// h32 f32 [2048,1024] master state (in place), hb16 bf16 shadow for GEMM A.
// ---------------------------------------------------------------------------
__global__ __launch_bounds__(256) void gru_combine(
    const u16* __restrict__ gi, const u16* __restrict__ gh,
    float* __restrict__ h32, u16* __restrict__ hb16)
{
  int idx = blockIdx.x * 256 + threadIdx.x;   // 0 .. 2048*128-1
  int m = idx >> 7;
  int j0 = (idx & 127) << 3;
  const size_t gb = (size_t)m * 3072 + j0;
  const size_t hb = (size_t)m * 1024 + j0;
  u16x8 ir = *(const u16x8*)&gi[gb];
  u16x8 iz = *(const u16x8*)&gi[gb + 1024];
  u16x8 in_ = *(const u16x8*)&gi[gb + 2048];
  u16x8 hr = *(const u16x8*)&gh[gb];
  u16x8 hz = *(const u16x8*)&gh[gb + 1024];
  u16x8 hn = *(const u16x8*)&gh[gb + 2048];
  f32x4 h0 = *(const f32x4*)&h32[hb];
  f32x4 h1v = *(const f32x4*)&h32[hb + 4];
  f32x4 o0, o1;
  u16x8 ob;
#pragma unroll
  for (int q = 0; q < 8; ++q) {
    float r = 1.f / (1.f + __expf(-(b2f(ir[q]) + b2f(hr[q]))));
    float z = 1.f / (1.f + __expf(-(b2f(iz[q]) + b2f(hz[q]))));
    float nn = tanhf(b2f(in_[q]) + r * b2f(hn[q]));
    float hh = (q < 4) ? h0[q & 3] : h1v[q & 3];
    float res = (1.f - z) * nn + z * hh;
    if (q < 4) o0[q & 3] = res; else o1[q & 3] = res;
    ob[q] = f2b(res);
  }
  *(f32x4*)&h32[hb] = o0;
  *(f32x4*)&h32[hb + 4] = o1;
  *(u16x8*)&hb16[hb] = ob;
}

// ---------------------------------------------------------------------------
extern "C" void kernel_launch(void* const* d_in, const int* in_sizes, int n_in,
                              void* d_out, int out_size, void* d_ws, size_t ws_size,
                              hipStream_t stream)
{
  const float* c      = (const float*)d_in[0];
  const float* target = (const float*)d_in[1];
  const float* fiw    = (const float*)d_in[4];
  const float* fib    = (const float*)d_in[5];
  const float* g1wih  = (const float*)d_in[6];
  const float* g1whh  = (const float*)d_in[7];
  const float* g1bih  = (const float*)d_in[8];
  const float* g1bhh  = (const float*)d_in[9];
  const float* g2wih  = (const float*)d_in[10];
  const float* g2whh  = (const float*)d_in[11];
  const float* g2bih  = (const float*)d_in[12];
  const float* g2bhh  = (const float*)d_in[13];
  const float* fcow   = (const float*)d_in[14];
  const float* fcob   = (const float*)d_in[15];
  float* out = (float*)d_out;

  char* wsp = (char*)d_ws;
  size_t off = 0;
  auto takeb = [&](size_t bytes) {
    void* p = (void*)(wsp + off);
    off += bytes;
    off = (off + 255) & ~(size_t)255;
    return p;
  };
  float* h1f = (float*)takeb((size_t)2048 * 1024 * 4);
  float* h2f = (float*)takeb((size_t)2048 * 1024 * 4);
  u16* h1b   = (u16*)takeb((size_t)2048 * 1024 * 2);
  u16* h2b   = (u16*)takeb((size_t)2048 * 1024 * 2);
  u16* gic   = (u16*)takeb((size_t)2048 * 3072 * 2);
  u16* gib   = (u16*)takeb((size_t)2048 * 3072 * 2);
  u16* gh1   = (u16*)takeb((size_t)2048 * 3072 * 2);
  u16* gh2   = (u16*)takeb((size_t)2048 * 3072 * 2);
  u16* cbf   = (u16*)takeb((size_t)2048 * 512 * 2);
  u16* Wfi   = (u16*)takeb((size_t)2048 * 512 * 2);
  u16* Wc    = (u16*)takeb((size_t)3072 * 512 * 2);
  u16* Wd    = (u16*)takeb((size_t)3072 * 160 * 2);
  u16* W1h   = (u16*)takeb((size_t)3072 * 1024 * 2);
  u16* W2i   = (u16*)takeb((size_t)3072 * 1024 * 2);
  u16* W2h   = (u16*)takeb((size_t)3072 * 1024 * 2);
  u16* WBy   = (u16*)takeb((size_t)256 * 1024 * 2);
  // total ~94 MiB
  (void)ws_size; (void)in_sizes; (void)n_in; (void)out_size;

  const int BIG = 1 << 30;   // n_split sentinel: always B0

  // --- one-time prep: conversions to bf16 ---
  cvt2<<<8192, 256, 0, stream>>>(c, fiw, cbf, Wfi);
  cvt3<<<36864, 256, 0, stream>>>(g1whh, g2wih, g2whh, W1h, W2i, W2h);
  prep_w1 <<<8064, 256, 0, stream>>>(g1wih, Wc, Wd);
  prep_wby<<<1024, 256, 0, stream>>>(fcow, WBy);

  // --- init ---
  // h1,h2 = tanh(c @ fiw.T + fib)  (f32 + bf16 shadow)
  gemm_bt<<<dim3(16, 16), 512, 0, stream>>>(cbf, 512, nullptr, Wfi, nullptr, 512, BIG,
                                            2048, 512, 1, 0, fib, nullptr,
                                            h1b, h2b, nullptr, h1f, h2f);
  // gi_c = c @ Wc.T + g1bih
  gemm_bt<<<dim3(24, 16), 512, 0, stream>>>(cbf, 512, nullptr, Wc, nullptr, 512, BIG,
                                            3072, 512, 0, 0, g1bih, nullptr,
                                            gic, nullptr, nullptr, nullptr, nullptr);
  // gh1 = h1 @ g1whh.T + g1bhh
  gemm_bt<<<dim3(24, 16), 512, 0, stream>>>(h1b, 1024, nullptr, W1h, nullptr, 1024, BIG,
                                            3072, 1024, 0, 0, g1bhh, nullptr,
                                            gh1, nullptr, nullptr, nullptr, nullptr);
  // gh2 = h2 @ g2whh.T + g2bhh
  gemm_bt<<<dim3(24, 16), 512, 0, stream>>>(h2b, 1024, nullptr, W2h, nullptr, 1024, BIG,
                                            3072, 1024, 0, 0, g2bhh, nullptr,
                                            gh2, nullptr, nullptr, nullptr, nullptr);

  // --- recurrence ---
  for (int t = 0; t < 16; ++t) {
    // gi1 = prev_t @ Wd.T + gi_c   (A read directly from target, shifted)
    gemm_bt<<<dim3(24, 16), 512, 0, stream>>>(nullptr, 160, target, Wd, nullptr, 160, BIG,
                                              3072, 160, 2, t, nullptr, nullptr,
                                              gib, nullptr, gic, nullptr, nullptr);
    gru_combine<<<1024, 256, 0, stream>>>(gib, gh1, h1f, h1b);   // h1 <- GRU1
    // gi2 = h1 @ g2wih.T + g2bih ; gh1_next = h1 @ g1whh.T + g1bhh
    gemm_bt<<<dim3(48, 16), 512, 0, stream>>>(h1b, 1024, nullptr, W2i, W1h, 1024, 3072,
                                              6144, 1024, 3, 0, g2bih, g1bhh,
                                              gib, gh1, nullptr, nullptr, nullptr);
    gru_combine<<<1024, 256, 0, stream>>>(gib, gh2, h2f, h2b);   // h2 <- GRU2
    // gh2_next = h2 @ g2whh.T + g2bhh ; y = h2 @ fco_w.T + fco_b -> out (f32)
    gemm_bt<<<dim3(26, 16), 512, 0, stream>>>(h2b, 1024, nullptr, W2h, WBy, 1024, 3072,
                                              3328, 1024, 4, t, g2bhh, fcob,
                                              gh2, nullptr, nullptr, out, nullptr);
  }
}